// Round 3
// baseline (21.306 us; speedup 1.0000x reference)
//
#include <hip/hip_runtime.h>
#include <hip/hip_fp16.h>
#include <stdint.h>

// out[8,8192] = x[8,8192] @ W.T, W[n,k] = nibble(Qidxs[n,k/8], INV[k%8]) - 7.5
// grid = 256 blocks x 512 threads (8 waves). Block owns 32 n-rows.
// Wave w computes K-eighth w (1024 K = 4 subchunks of 256 K).
// B: global -> registers directly (3 buffers, 2-deep prefetch, no LDS, no barriers).
// A: per-wave double-buffered LDS frag table (f32->f16 cvt once per subchunk).
// One __syncthreads at the end, 8-way LDS reduce, coalesced store.

typedef _Float16 half8 __attribute__((ext_vector_type(8)));
typedef float floatx16 __attribute__((ext_vector_type(16)));

union H2U { unsigned u; __half2 h; };
union V4H8 { uint4 u4; half8 h8; };

// (1024+n) exact -> -1024 -> -7.5  (all exact in f16)
__device__ __forceinline__ unsigned unpack_even(unsigned ws, __half2 c1, __half2 c2) {
    H2U t; t.u = (ws & 0x000F000Fu) | 0x64006400u;
    t.h = __hadd2(__hadd2(t.h, c1), c2);
    return t.u;
}
// (1024+16n) exact -> *1/16 - 71.5 = n - 7.5 (exact fma)
__device__ __forceinline__ unsigned unpack_odd(unsigned ws, __half2 cs, __half2 cc) {
    H2U t; t.u = (ws & 0x00F000F0u) | 0x64006400u;
    t.h = __hfma2(t.h, cs, cc);
    return t.u;
}

#define APITCH 272                    // 16 slots x 16B + zero slot, pitch 272B
#define ATBL   (16 * APITCH)          // 4352 B, one A table (16 K-steps)
#define NW     8
#define RED0   (NW * 2 * ATBL)        // 69632: A tables (8 waves x 2)
#define LDS_BYTES (RED0 + NW * 1024)  // 77824: + reduce area (8 waves x 8x32 f32)

__global__ __launch_bounds__(512, 2)
void hi4b_gemm(const float* __restrict__ x, const int* __restrict__ q,
               float* __restrict__ out)
{
    extern __shared__ char lds[];
    const int tid  = threadIdx.x;
    const int lane = tid & 63;
    const int wv   = tid >> 6;            // K-eighth 0..7
    const int n0   = blockIdx.x * 32;

    const int nlo = lane & 31;
    const int u   = lane >> 5;
    const int sh  = 8 * u;

    // B: per-lane row pointer. Subchunk sc word j lives at qrow[sc*8 + j/4].(j%4)
    const uint4* q4   = (const uint4*)q;                  // 256 uint4 per n-row
    const uint4* qrow = q4 + (n0 + nlo) * 256 + wv * 32;

    // A staging: slot = (uu, rr) over 16 lanes, shi picks steps 4i+shi
    const int slot = lane & 15, shi = lane >> 4;
    const int uu = slot >> 3, rr = slot & 7;
    const float4* x4   = (const float4*)x;                // 2048 float4 per b-row
    const float4* xrow = x4 + rr * 2048 + wv * 256 + uu;

    char* T0 = lds + wv * 2 * ATBL;
    char* T1 = T0 + ATBL;

    // zero slot per step (A rows 8..31 are padding) — written once
    if (lane < 16) {
        *(uint4*)(T0 + lane * APITCH + 256) = make_uint4(0u, 0u, 0u, 0u);
        *(uint4*)(T1 + lane * APITCH + 256) = make_uint4(0u, 0u, 0u, 0u);
    }

    uint4 B0[8], B1[8], B2[8];
    float4 ra[8];

    auto loadB = [&](uint4 (&b)[8], int sc) {
        #pragma unroll
        for (int i = 0; i < 8; ++i) b[i] = qrow[sc * 8 + i];
    };
    auto loadA = [&](int sc) {
        #pragma unroll
        for (int i = 0; i < 4; ++i) {
            int s = 4 * i + shi;
            ra[2 * i]     = xrow[sc * 64 + 4 * s];
            ra[2 * i + 1] = xrow[sc * 64 + 4 * s + 2];
        }
    };
    auto writeA = [&](char* T) {
        #pragma unroll
        for (int i = 0; i < 4; ++i) {
            int s = 4 * i + shi;
            H2U a0, a1, a2, a3;
            a0.h = __floats2half2_rn(ra[2*i].x,   ra[2*i].y);
            a1.h = __floats2half2_rn(ra[2*i].z,   ra[2*i].w);
            a2.h = __floats2half2_rn(ra[2*i+1].x, ra[2*i+1].y);
            a3.h = __floats2half2_rn(ra[2*i+1].z, ra[2*i+1].w);
            *(uint4*)(T + s * APITCH + slot * 16) = make_uint4(a0.u, a1.u, a2.u, a3.u);
        }
    };

    const __half2 c1 = __floats2half2_rn(-1024.0f, -1024.0f);
    const __half2 c2 = __floats2half2_rn(-7.5f, -7.5f);
    const __half2 cs = __floats2half2_rn(0.0625f, 0.0625f);
    const __half2 cc = __floats2half2_rn(-71.5f, -71.5f);

    floatx16 acc;
    #pragma unroll
    for (int i = 0; i < 16; ++i) acc[i] = 0.0f;

    const char* apL0 = T0 + ((nlo < 8) ? (u * 8 + nlo) * 16 : 256);
    const char* apL1 = T1 + ((nlo < 8) ? (u * 8 + nlo) * 16 : 256);

    auto compute = [&](const uint4 (&b)[8], const char* apL) {
        #pragma unroll
        for (int i = 0; i < 8; ++i) {
            uint4 w4 = b[i];
            {   // step s = 2i: words (x, y)
                V4H8 A;  A.u4 = *(const uint4*)(apL + (2 * i) * APITCH);
                unsigned wsa = w4.x >> sh, wsb = w4.y >> sh;
                V4H8 Bf;
                Bf.u4.x = unpack_even(wsa, c1, c2);
                Bf.u4.y = unpack_odd (wsa, cs, cc);
                Bf.u4.z = unpack_even(wsb, c1, c2);
                Bf.u4.w = unpack_odd (wsb, cs, cc);
                acc = __builtin_amdgcn_mfma_f32_32x32x16_f16(A.h8, Bf.h8, acc, 0, 0, 0);
            }
            {   // step s = 2i+1: words (z, w)
                V4H8 A;  A.u4 = *(const uint4*)(apL + (2 * i + 1) * APITCH);
                unsigned wsa = w4.z >> sh, wsb = w4.w >> sh;
                V4H8 Bf;
                Bf.u4.x = unpack_even(wsa, c1, c2);
                Bf.u4.y = unpack_odd (wsa, cs, cc);
                Bf.u4.z = unpack_even(wsb, c1, c2);
                Bf.u4.w = unpack_odd (wsb, cs, cc);
                acc = __builtin_amdgcn_mfma_f32_32x32x16_f16(A.h8, Bf.h8, acc, 0, 0, 0);
            }
        }
    };

    // ---- software pipeline: B 2-deep in regs, A 1-deep via alternating tables ----
    loadA(0);
    loadB(B0, 0); loadB(B1, 1); loadB(B2, 2);
    writeA(T0);              // table sc=0
    loadA(1);
    writeA(T1);              // table sc=1
    loadA(2);
    compute(B0, apL0);       // sc=0
    loadB(B0, 3);
    writeA(T0);              // table sc=2 (T0 reads done)
    loadA(3);
    compute(B1, apL1);       // sc=1
    writeA(T1);              // table sc=3
    compute(B2, apL0);       // sc=2
    compute(B0, apL1);       // sc=3

    // ---- cross-wave reduce: wave tiles are 8 b-rows x 32 n-cols ----
    {
        float* red = (float*)(lds + RED0 + wv * 1024);
        #pragma unroll
        for (int r = 0; r < 4; ++r)
            red[(r + 4 * u) * 32 + nlo] = acc[r];
    }
    __syncthreads();
    if (tid < 256) {
        const int b = tid >> 5, nl = tid & 31;
        const float* rd = (const float*)(lds + RED0);
        float sm = 0.0f;
        #pragma unroll
        for (int w = 0; w < NW; ++w)
            sm += rd[w * 256 + b * 32 + nl];
        out[b * 8192 + n0 + nl] = sm;
    }
}

extern "C" void kernel_launch(void* const* d_in, const int* in_sizes, int n_in,
                              void* d_out, int out_size, void* d_ws, size_t ws_size,
                              hipStream_t stream)
{
    const float* x = (const float*)d_in[0];
    const int*   q = (const int*)d_in[1];
    float* out = (float*)d_out;

    hipLaunchKernelGGL(hi4b_gemm, dim3(256), dim3(512), LDS_BYTES, stream,
                       x, q, out);
}

// Round 4
// 19.860 us; speedup vs baseline: 1.0728x; 1.0728x over previous
//
#include <hip/hip_runtime.h>
#include <hip/hip_fp16.h>
#include <stdint.h>

// out[8,8192] = x[8,8192] @ W.T, W[n,k] = nibble(Qidxs[n,k/8], INV[k%8]) - 7.5
// grid = 256 blocks x 512 threads (8 waves). Block owns 32 n-rows.
// Wave w computes K-eighth w (1024 K = 4 subchunks of 256 K).
// B: coalesced global->reg->LDS staging, per-wave double-buffered (round-1 pattern).
// A: per-wave DOUBLE-buffered LDS frag table (f32->f16 cvt at stage time).
// No barriers in main loop (all LDS wave-private); one __syncthreads + 8-way reduce.

typedef _Float16 half8 __attribute__((ext_vector_type(8)));
typedef float floatx16 __attribute__((ext_vector_type(16)));

union H2U { unsigned u; __half2 h; };
union V4H8 { uint4 u4; half8 h8; };

// (1024+n) exact -> -1024 -> -7.5  (all exact in f16)
__device__ __forceinline__ unsigned unpack_even(unsigned ws, __half2 c1, __half2 c2) {
    H2U t; t.u = (ws & 0x000F000Fu) | 0x64006400u;
    t.h = __hadd2(__hadd2(t.h, c1), c2);
    return t.u;
}
// (1024+16n) exact -> *1/16 - 71.5 = n - 7.5 (exact fma)
__device__ __forceinline__ unsigned unpack_odd(unsigned ws, __half2 cs, __half2 cc) {
    H2U t; t.u = (ws & 0x00F000F0u) | 0x64006400u;
    t.h = __hfma2(t.h, cs, cc);
    return t.u;
}

#define BPITCH 136                    // 32 words + 8B pad (2-way-free ds_read_b64)
#define BBUF   (32 * BPITCH)          // 4352 B: one B buffer (32 rows x 32 words)
#define APITCH 272                    // 16 slots x 16B + zero slot per step
#define ATBL   (16 * APITCH)          // 4352 B: one A table (16 K-steps)
#define NW     8
#define AB0    (NW * 2 * BBUF)        // 69632
#define RED0   (AB0 + NW * 2 * ATBL)  // 139264
#define LDS_BYTES (RED0 + NW * 1024)  // 147456

__global__ __launch_bounds__(512, 2)
void hi4b_gemm(const float* __restrict__ x, const int* __restrict__ q,
               float* __restrict__ out)
{
    extern __shared__ char lds[];
    const int tid  = threadIdx.x;
    const int lane = tid & 63;
    const int wv   = tid >> 6;            // K-eighth 0..7
    const int n0   = blockIdx.x * 32;

    const int nlo = lane & 31;
    const int u   = lane >> 5;
    const int sh  = 8 * u;
    const int c   = lane & 7;             // uint4 within row-subchunk
    const int r0  = lane >> 3;            // 0..7

    const uint4*  q4 = (const uint4*)q;   // 256 uint4 per n-row
    const float4* x4 = (const float4*)x;  // 2048 float4 per b-row

    const int qbase = (n0 + r0) * 256 + wv * 32 + c;
    const int slot = lane & 15, shi = lane >> 4;   // steps s = 4i+shi
    const int uu = slot >> 3, rr = slot & 7;
    const int xbase = rr * 2048 + wv * 256 + uu;

    char* Bw = lds + wv * 2 * BBUF;
    char* T0 = lds + AB0 + wv * 2 * ATBL;
    char* T1 = T0 + ATBL;

    // zero slot per step (A rows 8..31 are padding) — written once per table
    if (lane < 16) {
        *(uint4*)(T0 + lane * APITCH + 256) = make_uint4(0u, 0u, 0u, 0u);
        *(uint4*)(T1 + lane * APITCH + 256) = make_uint4(0u, 0u, 0u, 0u);
    }

    uint4 rb0, rb1, rb2, rb3;
    float4 ra[8];

    auto loadB = [&](int sc) {
        int b = qbase + sc * 8;
        rb0 = q4[b];
        rb1 = q4[b +  8 * 256];
        rb2 = q4[b + 16 * 256];
        rb3 = q4[b + 24 * 256];
    };
    auto writeB = [&](int d) {
        char* Bb = Bw + d * BBUF;
        char* p0 = Bb + (r0     ) * BPITCH + c * 16;
        char* p1 = Bb + (r0 +  8) * BPITCH + c * 16;
        char* p2 = Bb + (r0 + 16) * BPITCH + c * 16;
        char* p3 = Bb + (r0 + 24) * BPITCH + c * 16;
        *(uint2*)(p0)     = make_uint2(rb0.x, rb0.y);
        *(uint2*)(p0 + 8) = make_uint2(rb0.z, rb0.w);
        *(uint2*)(p1)     = make_uint2(rb1.x, rb1.y);
        *(uint2*)(p1 + 8) = make_uint2(rb1.z, rb1.w);
        *(uint2*)(p2)     = make_uint2(rb2.x, rb2.y);
        *(uint2*)(p2 + 8) = make_uint2(rb2.z, rb2.w);
        *(uint2*)(p3)     = make_uint2(rb3.x, rb3.y);
        *(uint2*)(p3 + 8) = make_uint2(rb3.z, rb3.w);
    };
    auto loadA = [&](int sc) {
        #pragma unroll
        for (int i = 0; i < 4; ++i) {
            int s = 4 * i + shi;
            int xi = xbase + sc * 64 + 4 * s;
            ra[2 * i]     = x4[xi];
            ra[2 * i + 1] = x4[xi + 2];
        }
    };
    auto writeA = [&](char* T) {
        #pragma unroll
        for (int i = 0; i < 4; ++i) {
            int s = 4 * i + shi;
            H2U a0, a1, a2, a3;
            a0.h = __floats2half2_rn(ra[2*i].x,   ra[2*i].y);
            a1.h = __floats2half2_rn(ra[2*i].z,   ra[2*i].w);
            a2.h = __floats2half2_rn(ra[2*i+1].x, ra[2*i+1].y);
            a3.h = __floats2half2_rn(ra[2*i+1].z, ra[2*i+1].w);
            *(uint4*)(T + s * APITCH + slot * 16) = make_uint4(a0.u, a1.u, a2.u, a3.u);
        }
    };

    const __half2 c1 = __floats2half2_rn(-1024.0f, -1024.0f);
    const __half2 c2 = __floats2half2_rn(-7.5f, -7.5f);
    const __half2 cs = __floats2half2_rn(0.0625f, 0.0625f);
    const __half2 cc = __floats2half2_rn(-71.5f, -71.5f);

    floatx16 acc;
    #pragma unroll
    for (int i = 0; i < 16; ++i) acc[i] = 0.0f;

    const int aoff = (nlo < 8) ? (u * 8 + nlo) * 16 : 256;
    const char* apL0 = T0 + aoff;
    const char* apL1 = T1 + aoff;

    auto compute = [&](int d, const char* apL) {
        const char* bp = Bw + d * BBUF + nlo * BPITCH;
        #pragma unroll
        for (int s = 0; s < 16; ++s) {
            uint2 w2 = *(const uint2*)(bp + s * 8);
            V4H8 A;  A.u4 = *(const uint4*)(apL + s * APITCH);
            unsigned wsa = w2.x >> sh;
            unsigned wsb = w2.y >> sh;
            V4H8 Bf;
            Bf.u4.x = unpack_even(wsa, c1, c2);
            Bf.u4.y = unpack_odd (wsa, cs, cc);
            Bf.u4.z = unpack_even(wsb, c1, c2);
            Bf.u4.w = unpack_odd (wsb, cs, cc);
            acc = __builtin_amdgcn_mfma_f32_32x32x16_f16(A.h8, Bf.h8, acc, 0, 0, 0);
        }
    };

    // ---- software pipeline over 4 subchunks, no barriers ----
    loadB(0); loadA(0);
    writeB(0); writeA(T0);        // sc0 staged
    loadB(1); loadA(1);
    writeB(1); writeA(T1);        // sc1 staged
    loadB(2); loadA(2);
    compute(0, apL0);             // sc0
    writeB(0); writeA(T0);        // sc2 -> buf0/T0 (sc0 reads done)
    loadB(3); loadA(3);
    compute(1, apL1);             // sc1
    writeB(1); writeA(T1);        // sc3 -> buf1/T1
    compute(0, apL0);             // sc2
    compute(1, apL1);             // sc3

    // ---- cross-wave reduce: wave tiles are 8 b-rows x 32 n-cols ----
    {
        float* red = (float*)(lds + RED0 + wv * 1024);
        #pragma unroll
        for (int r = 0; r < 4; ++r)
            red[(r + 4 * u) * 32 + nlo] = acc[r];
    }
    __syncthreads();
    if (tid < 256) {
        const int b = tid >> 5, nl = tid & 31;
        const float* rd = (const float*)(lds + RED0);
        float sm = 0.0f;
        #pragma unroll
        for (int w = 0; w < NW; ++w)
            sm += rd[w * 256 + b * 32 + nl];
        out[b * 8192 + n0 + nl] = sm;
    }
}

extern "C" void kernel_launch(void* const* d_in, const int* in_sizes, int n_in,
                              void* d_out, int out_size, void* d_ws, size_t ws_size,
                              hipStream_t stream)
{
    const float* x = (const float*)d_in[0];
    const int*   q = (const int*)d_in[1];
    float* out = (float*)d_out;

    hipLaunchKernelGGL(hi4b_gemm, dim3(256), dim3(512), LDS_BYTES, stream,
                       x, q, out);
}

// Round 5
// 15.965 us; speedup vs baseline: 1.3345x; 1.2439x over previous
//
#include <hip/hip_runtime.h>
#include <hip/hip_fp16.h>
#include <stdint.h>

// out[8,8192] = x[8,8192] @ W.T, W[n,k] = nibble(Qidxs[n,k/8], INV[k%8]) - 7.5
// grid = 256 blocks x 1024 threads (16 waves = 4/SIMD -> grid no longer caps occupancy).
// Block owns 32 n-rows; wave w owns K-window w*512..w*512+511 (2 subchunks of 256 K).
// Wave-private single-buffered B+A LDS, register prefetch 1 subchunk ahead,
// ZERO barriers in main loop (same-wave DS ops are in-order -> LDS WAR safe).
// End: barrier, 16-way LDS reduce (aliased over staging LDS), coalesced store.

typedef _Float16 half8 __attribute__((ext_vector_type(8)));
typedef float floatx16 __attribute__((ext_vector_type(16)));

union H2U { unsigned u; __half2 h; };
union V4H8 { uint4 u4; half8 h8; };

// (1024+n) exact -> -1024 -> -7.5  (all exact in f16)
__device__ __forceinline__ unsigned unpack_even(unsigned ws, __half2 c1, __half2 c2) {
    H2U t; t.u = (ws & 0x000F000Fu) | 0x64006400u;
    t.h = __hadd2(__hadd2(t.h, c1), c2);
    return t.u;
}
// (1024+16n) exact -> *1/16 - 71.5 = n - 7.5 (exact fma)
__device__ __forceinline__ unsigned unpack_odd(unsigned ws, __half2 cs, __half2 cc) {
    H2U t; t.u = (ws & 0x00F000F0u) | 0x64006400u;
    t.h = __hfma2(t.h, cs, cc);
    return t.u;
}

#define BPITCH 136                 // 32 words + 8B pad (2-way-free ds_read_b64)
#define BBUF   (32 * BPITCH)       // 4352 B: B buffer (32 rows x 32 words)
#define APITCH 272                 // 16 slots x 16B + zero slot per step
#define ATBL   (16 * APITCH)       // 4352 B: A table (16 K-steps)
#define WLDS   (BBUF + ATBL)       // 8704 B per wave
#define NW     16
#define LDS_BYTES (NW * WLDS)      // 139264 (reduce area aliased at offset 0)

__global__ __launch_bounds__(1024, 4)
void hi4b_gemm(const float* __restrict__ x, const int* __restrict__ q,
               float* __restrict__ out)
{
    extern __shared__ char lds[];
    const int tid  = threadIdx.x;
    const int lane = tid & 63;
    const int wv   = tid >> 6;            // 0..15: K-window wv*512
    const int n0   = blockIdx.x * 32;

    const int nlo = lane & 31;
    const int u   = lane >> 5;
    const int sh  = 8 * u;
    const int c   = lane & 7;             // uint4 within row-subchunk
    const int r0  = lane >> 3;            // 0..7

    const uint4*  q4 = (const uint4*)q;   // 256 uint4 per n-row
    const float4* x4 = (const float4*)x;  // 2048 float4 per b-row

    const int qbase = (n0 + r0) * 256 + wv * 16 + c;     // wv*512k = 16 uint4
    const int slot = lane & 15, shi = lane >> 4;          // steps s = 4i+shi
    const int uu = slot >> 3, rr = slot & 7;
    const int xbase = rr * 2048 + wv * 128 + uu;          // wv*512k = 128 float4

    char* Bw = lds + wv * WLDS;
    char* Aw = Bw + BBUF;

    // zero slot per step (A rows 8..31 are padding) — written once, never overwritten
    if (lane < 16)
        *(uint4*)(Aw + lane * APITCH + 256) = make_uint4(0u, 0u, 0u, 0u);

    uint4 rb0, rb1, rb2, rb3;
    float4 ra[8];

    auto loadB = [&](int sc) {
        int b = qbase + sc * 8;                 // subchunk = 256k = 8 uint4
        rb0 = q4[b];
        rb1 = q4[b +  8 * 256];
        rb2 = q4[b + 16 * 256];
        rb3 = q4[b + 24 * 256];
    };
    auto writeB = [&]() {
        char* p0 = Bw + (r0     ) * BPITCH + c * 16;
        char* p1 = Bw + (r0 +  8) * BPITCH + c * 16;
        char* p2 = Bw + (r0 + 16) * BPITCH + c * 16;
        char* p3 = Bw + (r0 + 24) * BPITCH + c * 16;
        *(uint2*)(p0)     = make_uint2(rb0.x, rb0.y);
        *(uint2*)(p0 + 8) = make_uint2(rb0.z, rb0.w);
        *(uint2*)(p1)     = make_uint2(rb1.x, rb1.y);
        *(uint2*)(p1 + 8) = make_uint2(rb1.z, rb1.w);
        *(uint2*)(p2)     = make_uint2(rb2.x, rb2.y);
        *(uint2*)(p2 + 8) = make_uint2(rb2.z, rb2.w);
        *(uint2*)(p3)     = make_uint2(rb3.x, rb3.y);
        *(uint2*)(p3 + 8) = make_uint2(rb3.z, rb3.w);
    };
    auto loadA = [&](int sc) {
        #pragma unroll
        for (int i = 0; i < 4; ++i) {
            int s = 4 * i + shi;
            int xi = xbase + sc * 64 + 4 * s;   // subchunk = 64 float4
            ra[2 * i]     = x4[xi];
            ra[2 * i + 1] = x4[xi + 2];
        }
    };
    auto writeA = [&]() {
        #pragma unroll
        for (int i = 0; i < 4; ++i) {
            int s = 4 * i + shi;
            H2U a0, a1, a2, a3;
            a0.h = __floats2half2_rn(ra[2*i].x,   ra[2*i].y);
            a1.h = __floats2half2_rn(ra[2*i].z,   ra[2*i].w);
            a2.h = __floats2half2_rn(ra[2*i+1].x, ra[2*i+1].y);
            a3.h = __floats2half2_rn(ra[2*i+1].z, ra[2*i+1].w);
            *(uint4*)(Aw + s * APITCH + slot * 16) = make_uint4(a0.u, a1.u, a2.u, a3.u);
        }
    };

    const __half2 c1 = __floats2half2_rn(-1024.0f, -1024.0f);
    const __half2 c2 = __floats2half2_rn(-7.5f, -7.5f);
    const __half2 cs = __floats2half2_rn(0.0625f, 0.0625f);
    const __half2 cc = __floats2half2_rn(-71.5f, -71.5f);

    floatx16 acc;
    #pragma unroll
    for (int i = 0; i < 16; ++i) acc[i] = 0.0f;

    const int aoff = (nlo < 8) ? (u * 8 + nlo) * 16 : 256;
    const char* ap = Aw + aoff;
    const char* bp = Bw + nlo * BPITCH;

    auto compute = [&]() {
        #pragma unroll
        for (int s = 0; s < 16; ++s) {
            uint2 w2 = *(const uint2*)(bp + s * 8);
            V4H8 A;  A.u4 = *(const uint4*)(ap + s * APITCH);
            unsigned wsa = w2.x >> sh;
            unsigned wsb = w2.y >> sh;
            V4H8 Bf;
            Bf.u4.x = unpack_even(wsa, c1, c2);
            Bf.u4.y = unpack_odd (wsa, cs, cc);
            Bf.u4.z = unpack_even(wsb, c1, c2);
            Bf.u4.w = unpack_odd (wsb, cs, cc);
            acc = __builtin_amdgcn_mfma_f32_32x32x16_f16(A.h8, Bf.h8, acc, 0, 0, 0);
        }
    };

    // ---- pipeline over 2 subchunks, zero barriers ----
    loadB(0); loadA(0);
    writeB(); writeA();        // stage sc0 (waits on loads0)
    loadB(1); loadA(1);        // prefetch sc1 into same regs (issued before compute)
    compute();                 // consume sc0 from LDS
    writeB(); writeA();        // stage sc1 (in-order DS => WAR vs compute reads safe)
    compute();                 // consume sc1

    // ---- cross-wave reduce: 16 tiles of 8 b-rows x 32 n-cols, aliased over staging LDS ----
    __syncthreads();
    {
        float* red = (float*)lds + wv * 256;
        #pragma unroll
        for (int r = 0; r < 4; ++r)
            red[(r + 4 * u) * 32 + nlo] = acc[r];
    }
    __syncthreads();
    if (tid < 256) {
        const int b = tid >> 5, nl = tid & 31;
        const float* rd = (const float*)lds;
        float sm = 0.0f;
        #pragma unroll
        for (int w = 0; w < NW; ++w)
            sm += rd[w * 256 + b * 32 + nl];
        out[b * 8192 + n0 + nl] = sm;
    }
}

extern "C" void kernel_launch(void* const* d_in, const int* in_sizes, int n_in,
                              void* d_out, int out_size, void* d_ws, size_t ws_size,
                              hipStream_t stream)
{
    const float* x = (const float*)d_in[0];
    const int*   q = (const int*)d_in[1];
    float* out = (float*)d_out;

    hipLaunchKernelGGL(hi4b_gemm, dim3(256), dim3(1024), LDS_BYTES, stream,
                       x, q, out);
}